// Round 9
// baseline (102.969 us; speedup 1.0000x reference)
//
#include <hip/hip_runtime.h>
#include <math.h>

// Problem: B=4, N=8192, Din=Dout=128 fp32.
// out[b][o] = (1/128) * sum_i max_n ( x[b][n][i] * sigmoid(x@W+b)[b][n][o] )
#define D 128
#define NNODES 8192
#define NBATCH 4
#define RW 132          // padded LDS row width (uints) -> bank spread

typedef _Float16 f16x8 __attribute__((ext_vector_type(8)));
typedef _Float16 f16x2 __attribute__((ext_vector_type(2)));
typedef float f32x4 __attribute__((ext_vector_type(4)));

__device__ inline f16x2 bc(unsigned int v) { return __builtin_bit_cast(f16x2, v); }
__device__ inline unsigned int cb(f16x2 v) { return __builtin_bit_cast(unsigned int, v); }
__device__ inline f16x2 pkmax(f16x2 a, f16x2 b) {
    return __builtin_elementwise_max(a, b);   // v_pk_max_f16
}
// max of the two halves of a packed f16x2, result in low 16 bits
__device__ inline unsigned int fold2(unsigned int a) {
    return cb(pkmax(bc(a), bc(a >> 16))) & 0xFFFFu;
}

// ---------------------------------------------------------------------------
// MFMA B-fragments of W^T as fp16; one coalesced dwordx4 per lane:
//   wfrag[(ot*4 + ks)*64 + lane] = W[k][o] halves,
//   o = ot*16 + (lane&15), k = ks*32 + (lane>>4)*8 + j (j=0..7).
// 32 KB, L2/L3-resident. Also zeroes d_out (saves a memset dispatch).
// ---------------------------------------------------------------------------
__global__ __launch_bounds__(256) void wfrag_kernel(
    const float* __restrict__ W, uint4* __restrict__ wfrag,
    float* __restrict__ out)
{
    int e    = blockIdx.x * 256 + threadIdx.x;   // 0..2047
    if (e < NBATCH * D) out[e] = 0.0f;           // zero d_out (512 floats)
    int lane = e & 63, ks = (e >> 6) & 3, ot = e >> 8;
    int o  = ot * 16 + (lane & 15);
    int kb = ks * 32 + (lane >> 4) * 8;
    f16x8 f;
#pragma unroll
    for (int j = 0; j < 8; ++j) f[j] = (_Float16)W[(kb + j) * D + o];
    wfrag[e] = __builtin_bit_cast(uint4, f);
}

// ---------------------------------------------------------------------------
// Fused gate+pool. grid 1024 = B*256 slices of 32 nodes; 256 threads.
// LDS = 2 * 8.45 KB = 16.9 KB -> 4 blocks/CU (VGPR-capped 128 via
// launch_bounds(256,4)) = 16 waves/CU, 2x R8's latency hiding. All 1024
// blocks resident in one round.
//
// Phase 1 (MFMA): wave w: node-stripe = w&1 (16 nodes), o-half = w>>1.
//   A-frags extracted from node-pair-packed xh2 via v_perm (lane parity
//   selects lo/hi half). B-frags double-buffered from wfrag; first group
//   prefetched BEFORE staging (no dependency). 16 MFMA/wave.
//   C/D: col=lane&15, row=quad*4+reg (m89; verified R5-R8 passing).
// Phase 2 (pool): fully unrolled 16 node-pairs, 8i x 8o per thread,
//   v_pk_mul_f16 + v_pk_max_f16. Slab fp16 [i][o] = 32 KB per block.
// ---------------------------------------------------------------------------
__global__ __launch_bounds__(256, 4) void fused_gate_pool(
    const float* __restrict__ x, const float* __restrict__ bias,
    const uint4* __restrict__ wfrag, uint2* __restrict__ slab)
{
    __shared__ unsigned int xh2[16 * RW];   // 8.45 KB node-pair f16x2
    __shared__ unsigned int gh2[16 * RW];   // 8.45 KB gate node-pair f16x2

    const int t    = threadIdx.x;
    const int blk  = blockIdx.x;            // b*256 + slice
    const size_t base = (size_t)blk * 32 * D;
    const int lane = t & 63, wave = t >> 6;
    const int quad = lane >> 4, col = lane & 15;
    const int stripe = wave & 1, oh = wave >> 1;

    // early prefetch of first B-frag group (independent of staging)
    uint4 bf[4];
#pragma unroll
    for (int ks = 0; ks < 4; ++ks)
        bf[ks] = wfrag[((oh * 4 + 0) * 4 + ks) * 64 + lane];

    // ---- stage x once: pack node-pairs to f16x2 ----
    const float4* xs4 = (const float4*)(x + base);
#pragma unroll
    for (int it = 0; it < 2; ++it) {
        int idx = t + 256 * it;             // 0..511
        int p = idx >> 5, c4 = idx & 31;    // pair row (0..15), feature quad
        float4 a = xs4[(2 * p) * 32 + c4];      // even node
        float4 b = xs4[(2 * p + 1) * 32 + c4];  // odd node
        uint4 u;
        u.x = cb((f16x2){(_Float16)a.x, (_Float16)b.x});
        u.y = cb((f16x2){(_Float16)a.y, (_Float16)b.y});
        u.z = cb((f16x2){(_Float16)a.z, (_Float16)b.z});
        u.w = cb((f16x2){(_Float16)a.w, (_Float16)b.w});
        *(uint4*)&xh2[p * RW + c4 * 4] = u;
    }
    __syncthreads();

    // ---- phase 1: MFMA GEMM + sigmoid -> gh2 ----
    const unsigned int sel = (col & 1) ? 0x07060302u : 0x05040100u;
    const int prow = stripe * 8 + (col >> 1);

    f16x8 af[4];
#pragma unroll
    for (int ks = 0; ks < 4; ++ks) {
        int kb = ks * 32 + quad * 8;        // feature base (= uint index)
        uint4 u0 = *(const uint4*)&xh2[prow * RW + kb];
        uint4 u1 = *(const uint4*)&xh2[prow * RW + kb + 4];
        uint4 r;
        r.x = __builtin_amdgcn_perm(u0.y, u0.x, sel);
        r.y = __builtin_amdgcn_perm(u0.w, u0.z, sel);
        r.z = __builtin_amdgcn_perm(u1.y, u1.x, sel);
        r.w = __builtin_amdgcn_perm(u1.w, u1.z, sel);
        af[ks] = __builtin_bit_cast(f16x8, r);
    }

    f32x4 acc[4];
#pragma unroll
    for (int ot = 0; ot < 4; ++ot) acc[ot] = (f32x4){0.f, 0.f, 0.f, 0.f};

#pragma unroll
    for (int ot = 0; ot < 4; ++ot) {
        uint4 cur[4];
#pragma unroll
        for (int ks = 0; ks < 4; ++ks) cur[ks] = bf[ks];
        if (ot < 3) {
#pragma unroll
            for (int ks = 0; ks < 4; ++ks)
                bf[ks] = wfrag[((oh * 4 + ot + 1) * 4 + ks) * 64 + lane];
        }
#pragma unroll
        for (int ks = 0; ks < 4; ++ks)
            acc[ot] = __builtin_amdgcn_mfma_f32_16x16x32_f16(
                af[ks], __builtin_bit_cast(f16x8, cur[ks]), acc[ot], 0, 0, 0);
    }

#pragma unroll
    for (int ot = 0; ot < 4; ++ot) {
        int o = oh * 64 + ot * 16 + col;
        float bv = bias[o];
#pragma unroll
        for (int rr = 0; rr < 2; ++rr) {    // nodes (2rr, 2rr+1) of this lane
            float g0 = 1.0f / (1.0f + __expf(-(acc[ot][2 * rr]     + bv)));
            float g1 = 1.0f / (1.0f + __expf(-(acc[ot][2 * rr + 1] + bv)));
            gh2[(stripe * 8 + quad * 2 + rr) * RW + o] =
                cb((f16x2){(_Float16)g0, (_Float16)g1});
        }
    }
    __syncthreads();

    // ---- phase 2: packed-fp16 max pool, fully unrolled over 16 pairs ----
    const int ti = t >> 4;   // i segs {ti*4..+3} U {64+ti*4..+3}
    const int to = t & 15;   // o segs {to*4..+3} U {64+to*4..+3}

    f16x2 pa[8][8];
#pragma unroll
    for (int ii = 0; ii < 8; ++ii)
#pragma unroll
        for (int oo = 0; oo < 8; ++oo) pa[ii][oo] = bc(0xFC00FC00u);

    const unsigned int* xpi = &xh2[ti * 4];
    const unsigned int* gpi = &gh2[to * 4];
#pragma unroll
    for (int p = 0; p < 16; ++p) {
        uint4 xa = *(const uint4*)&xpi[p * RW];
        uint4 xb = *(const uint4*)&xpi[p * RW + 64];
        uint4 ga = *(const uint4*)&gpi[p * RW];
        uint4 gb = *(const uint4*)&gpi[p * RW + 64];
        f16x2 xv[8] = {bc(xa.x), bc(xa.y), bc(xa.z), bc(xa.w),
                       bc(xb.x), bc(xb.y), bc(xb.z), bc(xb.w)};
        f16x2 gv[8] = {bc(ga.x), bc(ga.y), bc(ga.z), bc(ga.w),
                       bc(gb.x), bc(gb.y), bc(gb.z), bc(gb.w)};
#pragma unroll
        for (int ii = 0; ii < 8; ++ii)
#pragma unroll
            for (int oo = 0; oo < 8; ++oo)
                pa[ii][oo] = pkmax(pa[ii][oo], xv[ii] * gv[oo]);
    }

    // fold even/odd-node halves and store fp16 slab [i][o] (32 KB/block)
    uint2* sd = slab + (size_t)blk * 4096;
#pragma unroll
    for (int ii = 0; ii < 8; ++ii) {
        int ip = (ii < 4) ? (ti * 4 + ii) : (64 + ti * 4 + (ii - 4));
        unsigned int a[8];
#pragma unroll
        for (int oo = 0; oo < 8; ++oo) a[oo] = cb(pa[ii][oo]);
        unsigned int r01 = fold2(a[0]) | (fold2(a[1]) << 16);
        unsigned int r23 = fold2(a[2]) | (fold2(a[3]) << 16);
        unsigned int r45 = fold2(a[4]) | (fold2(a[5]) << 16);
        unsigned int r67 = fold2(a[6]) | (fold2(a[7]) << 16);
        uint2 v0 = {r01, r23};
        uint2 v1 = {r45, r67};
        sd[ip * 32 + to]      = v0;   // o = to*4..+3
        sd[ip * 32 + 16 + to] = v1;   // o = 64+to*4..+3
    }
}

// ---------------------------------------------------------------------------
// Reduce: out[b][o] = (1/128) * sum_i max over 256 slabs (fp16, pk_max).
// grid 512 = (b, i); 256 thr = 64 o-pairs x 4 s-groups; 256 B/wave rows,
// slab stride 8192 uints (32 KB).
// ---------------------------------------------------------------------------
__global__ __launch_bounds__(256) void reduce_kernel(
    const unsigned int* __restrict__ slab, float* __restrict__ out)
{
    __shared__ unsigned int red[3][64];
    const int rb = blockIdx.x;        // 0..511
    const int b  = rb >> 7, i = rb & 127;
    const int t  = threadIdx.x;
    const int og = t & 63, sg = t >> 6;

    const unsigned int* p =
        slab + (size_t)(b * 256 + sg * 64) * 8192 + i * 64 + og;
    f16x2 m = bc(0xFC00FC00u);
#pragma unroll 8
    for (int it = 0; it < 64; ++it)
        m = pkmax(m, bc(p[(size_t)it * 8192]));

    if (sg) red[sg - 1][og] = cb(m);
    __syncthreads();
    if (sg == 0) {
        m = pkmax(m, bc(red[0][og]));
        m = pkmax(m, bc(red[1][og]));
        m = pkmax(m, bc(red[2][og]));
        atomicAdd(&out[b * D + og * 2],     (float)m[0] * 0.0078125f);
        atomicAdd(&out[b * D + og * 2 + 1], (float)m[1] * 0.0078125f);
    }
}

// ---------------------------------------------------------------------------
extern "C" void kernel_launch(void* const* d_in, const int* in_sizes, int n_in,
                              void* d_out, int out_size, void* d_ws, size_t ws_size,
                              hipStream_t stream)
{
    const float* x    = (const float*)d_in[0];   // (4, 8192, 128)
    const float* W    = (const float*)d_in[1];   // (128, 128)
    const float* bias = (const float*)d_in[2];   // (128,)
    float* out = (float*)d_out;                  // (4, 128)

    uint4* wfrag = (uint4*)d_ws;                             // 32 KB
    uint2* slab  = (uint2*)((char*)d_ws + 65536);            // 1024 * 32 KB = 32 MB

    wfrag_kernel<<<8, 256, 0, stream>>>(W, wfrag, out);      // also zeroes out
    fused_gate_pool<<<1024, 256, 0, stream>>>(x, bias, wfrag, slab);
    reduce_kernel<<<512, 256, 0, stream>>>((const unsigned int*)slab, out);
}